// Round 7
// baseline (454.122 us; speedup 1.0000x reference)
//
#include <hip/hip_runtime.h>

#define SEQ 2048
#define NHEADS 16

typedef __bf16 bf16;
typedef __bf16 bf16x8 __attribute__((ext_vector_type(8)));
typedef __bf16 bf16x4v __attribute__((ext_vector_type(4)));
typedef float f32x4 __attribute__((ext_vector_type(4)));
typedef float f32x16 __attribute__((ext_vector_type(16)));
typedef unsigned short u16x4 __attribute__((ext_vector_type(4)));
typedef unsigned short u16x8 __attribute__((ext_vector_type(8)));

static __device__ __forceinline__ float bf2f(unsigned short u) {
    union { unsigned u32; float f; } v; v.u32 = ((unsigned)u) << 16; return v.f;
}
static __device__ __forceinline__ unsigned short f2bf(float f) {
    union { float f; unsigned u; } v; v.f = f;
    unsigned u = v.u;
    unsigned r = u + 0x7fffu + ((u >> 16) & 1u);  // RNE
    return (unsigned short)(r >> 16);
}

// CK-style direct global->LDS 16B copy. LDS dest = wave-uniform base + lane*16.
static __device__ __forceinline__ void g2l16(const unsigned short* g, unsigned short* l) {
    __builtin_amdgcn_global_load_lds(
        (const __attribute__((address_space(1))) unsigned int*)(unsigned long long)g,
        (__attribute__((address_space(3))) unsigned int*)(unsigned int)(unsigned long long)l,
        16, 0, 0);
}

// ---------------------------------------------------------------------------
__global__ void detect_dtype(const unsigned* __restrict__ qnw, int* __restrict__ flag) {
    if (threadIdx.x == 0 && blockIdx.x == 0)
        *flag = (qnw[0] == 0x3F800000u) ? 1 : 0;
}

struct CvtArgs {
    const void* src[13];
    unsigned short* dst[13];
    int n[13];
    int startblk[14];
};
// all n[] are multiples of 16, so vector tails are clean
__global__ __launch_bounds__(256) void to_bf16_all(CvtArgs a, const int* __restrict__ flag) {
    int bx = blockIdx.x;
    int t = 0;
    while (bx >= a.startblk[t + 1]) ++t;
    int base = (bx - a.startblk[t]) * 4096;
    int n = a.n[t];
    int hi = base + 4096; if (hi > n) hi = n;
    int cnt = hi - base;
    if (*flag) {
        const f32x4* s = (const f32x4*)a.src[t] + (base >> 2);
        u16x4* d = (u16x4*)(a.dst[t] + base);
        int c4 = cnt >> 2;
        for (int e = threadIdx.x; e < c4; e += 256) {
            f32x4 v = s[e];
            u16x4 o;
#pragma unroll
            for (int j = 0; j < 4; ++j) o[j] = f2bf(v[j]);
            d[e] = o;
        }
    } else {
        const uint4* s = (const uint4*)a.src[t] + (base >> 3);
        uint4* d = (uint4*)(a.dst[t] + base);
        int c8 = cnt >> 3;
        for (int e = threadIdx.x; e < c8; e += 256) d[e] = s[e];
    }
}

// ---------------------------------------------------------------------------
// m97-structure GEMM body, round-2 pipeline (measured best): double-buffered
// LDS, stage(next) issued before compute(cur), ONE __syncthreads per K-step.
// ---------------------------------------------------------------------------
struct GemmP {
    const unsigned short* A; int lda;
    const unsigned short* W;
    const unsigned short* bias;
    unsigned short* C; float* Cf; int ldc;
    int N; int K; const int* flagp;
    int nbx;      // tiles along N
    float oscale; // epilogue scale: out = (acc + bias) * oscale
};

static __device__ void gemm_body(const GemmP g, int bx, int by,
                                 unsigned short* Al, unsigned short* Bl)
{
    const int lane = threadIdx.x & 63;
    const int w    = threadIdx.x >> 6;
    const int r    = lane & 15;
    const int quad = lane >> 4;
    const int m0 = by << 7;
    const int n0 = bx << 7;
    const int wr = (w >> 1) << 6;
    const int wc = (w & 1) << 6;

    const int srow = lane >> 2;
    const int scol = (lane & 3) << 3;
    const int j0 = w * 2, j1 = w * 2 + 1;

    const unsigned short* a0 = g.A + (size_t)(m0 + j0 * 16 + srow) * g.lda + scol;
    const unsigned short* a1 = g.A + (size_t)(m0 + j1 * 16 + srow) * g.lda + scol;
    int bn0 = n0 + j0 * 16 + srow; if (bn0 >= g.N) bn0 = g.N - 1;
    int bn1 = n0 + j1 * 16 + srow; if (bn1 >= g.N) bn1 = g.N - 1;
    const unsigned short* b0 = g.W + (size_t)bn0 * g.K + scol;
    const unsigned short* b1 = g.W + (size_t)bn1 * g.K + scol;

    f32x4 acc[4][4];
#pragma unroll
    for (int mt = 0; mt < 4; ++mt)
#pragma unroll
        for (int nt = 0; nt < 4; ++nt) acc[mt][nt] = (f32x4){0.f, 0.f, 0.f, 0.f};

    auto stage = [&](int buf, int kb) {
        unsigned short* Ad = Al + (buf << 12);
        unsigned short* Bd = Bl + (buf << 12);
        g2l16(a0 + kb, &Ad[j0 * 512 + lane * 8]);
        g2l16(a1 + kb, &Ad[j1 * 512 + lane * 8]);
        g2l16(b0 + kb, &Bd[j0 * 512 + lane * 8]);
        g2l16(b1 + kb, &Bd[j1 * 512 + lane * 8]);
    };

    stage(0, 0);
    __syncthreads();
    int cur = 0;
    for (int kb = 0; kb < g.K; kb += 32) {
        if (kb + 32 < g.K) stage(cur ^ 1, kb + 32);   // loads fly under compute

        const unsigned short* As = Al + (cur << 12);
        const unsigned short* Bs = Bl + (cur << 12);
        bf16x8 af[4], bfr[4];
#pragma unroll
        for (int mt = 0; mt < 4; ++mt)
            af[mt] = *(const bf16x8*)&As[(wr + mt * 16 + r) * 32 + quad * 8];
#pragma unroll
        for (int nt = 0; nt < 4; ++nt)
            bfr[nt] = *(const bf16x8*)&Bs[(wc + nt * 16 + r) * 32 + quad * 8];
#pragma unroll
        for (int mt = 0; mt < 4; ++mt)
#pragma unroll
            for (int nt = 0; nt < 4; ++nt)
                acc[mt][nt] = __builtin_amdgcn_mfma_f32_16x16x32_bf16(af[mt], bfr[nt], acc[mt][nt], 0, 0, 0);

        __syncthreads();   // drains next-tile loads + protects cur
        cur ^= 1;
    }

    int outf = (g.Cf && g.flagp) ? *g.flagp : 0;
    float bv[4];
#pragma unroll
    for (int nt = 0; nt < 4; ++nt) {
        int col = n0 + wc + nt * 16 + r;
        bv[nt] = (g.bias && col < g.N) ? bf2f(g.bias[col]) : 0.f;
    }
#pragma unroll
    for (int mt = 0; mt < 4; ++mt) {
#pragma unroll
        for (int i = 0; i < 4; ++i) {
            int row = m0 + wr + mt * 16 + quad * 4 + i;
#pragma unroll
            for (int nt = 0; nt < 4; ++nt) {
                int col = n0 + wc + nt * 16 + r;
                if (col < g.N) {
                    float v = (acc[mt][nt][i] + bv[nt]) * g.oscale;
                    size_t idx = (size_t)row * g.ldc + col;
                    if (g.Cf) {
                        if (outf) g.Cf[idx] = v;
                        else      ((unsigned short*)g.Cf)[idx] = f2bf(v);
                    } else {
                        g.C[idx] = f2bf(v);
                    }
                }
            }
        }
    }
}

__global__ __launch_bounds__(256) void gemm_one(GemmP g) {
    __shared__ unsigned short Al[2 * 4096];
    __shared__ unsigned short Bl[2 * 4096];
    gemm_body(g, blockIdx.x, blockIdx.y, Al, Bl);
}

__global__ __launch_bounds__(256) void gemm_two(GemmP g0, GemmP g1, int nblk0) {
    __shared__ unsigned short Al[2 * 4096];
    __shared__ unsigned short Bl[2 * 4096];
    int id = blockIdx.x;
    if (id < nblk0) {
        gemm_body(g0, id % g0.nbx, id / g0.nbx, Al, Bl);
    } else {
        id -= nblk0;
        gemm_body(g1, id % g1.nbx, id / g1.nbx, Al, Bl);
    }
}

// ---------------------------------------------------------------------------
// fused rmsnorm for both lora paths (one launch), bf16x8-vectorized (G13)
__global__ __launch_bounds__(256) void rmsnorm_ip2(
    unsigned short* __restrict__ d0, int s0w, int w0w, const unsigned short* __restrict__ w0,
    unsigned short* __restrict__ d1, int s1w, int w1w, const unsigned short* __restrict__ w1,
    int rows0)
{
    __shared__ float red[256];
    int row = blockIdx.x;
    unsigned short* p; const unsigned short* wt; int stride, width;
    if (row < rows0) { p = d0; wt = w0; stride = s0w; width = w0w; }
    else { row -= rows0; p = d1; wt = w1; stride = s1w; width = w1w; }
    p += (size_t)row * stride;

    const int nv = width >> 3;
    u16x8* pv = (u16x8*)p;
    const u16x8* wv = (const u16x8*)wt;

    float ss = 0.f;
    for (int j = threadIdx.x; j < nv; j += 256) {
        u16x8 v = pv[j];
#pragma unroll
        for (int k = 0; k < 8; ++k) { float f = bf2f(v[k]); ss += f * f; }
    }
    red[threadIdx.x] = ss;
    __syncthreads();
    for (int s = 128; s > 0; s >>= 1) {
        if ((int)threadIdx.x < s) red[threadIdx.x] += red[threadIdx.x + s];
        __syncthreads();
    }
    float rstd = rsqrtf(red[0] / (float)width + 1e-6f);
    for (int j = threadIdx.x; j < nv; j += 256) {
        u16x8 v = pv[j], g = wv[j], o;
#pragma unroll
        for (int k = 0; k < 8; ++k) o[k] = f2bf(bf2f(v[k]) * rstd * bf2f(g[k]));
        pv[j] = o;
    }
}

// fused rope: 32-entry sincos LDS table per row (1 sincos per i, not per task)
__global__ __launch_bounds__(256) void rope_ip_all(
    unsigned short* __restrict__ qbuf, unsigned short* __restrict__ kvbf)
{
    __shared__ float cst[32], snt[32];
    int row = blockIdx.x;
    int s = row & (SEQ - 1);
    if (threadIdx.x < 32) {
        int i = threadIdx.x;
        float inv = exp2f(-(float)i * (13.2877123795f / 32.0f)); // 10000^(-i/32)
        float ang = (float)s * inv;
        cst[i] = cosf(ang); snt[i] = sinf(ang);
    }
    __syncthreads();
    for (int t = threadIdx.x; t < 544; t += 256) {
        int i = t & 31;
        float c = cst[i], sn = snt[i];
        unsigned short* p;
        if (t < 512) p = qbuf + (size_t)row * 3072 + (t >> 5) * 192 + 128;
        else         p = kvbf + (size_t)row * 576 + 512;
        float x1 = bf2f(p[i]), x2 = bf2f(p[i + 32]);
        p[i]      = f2bf(x1 * c - x2 * sn);
        p[i + 32] = f2bf(x2 * c + x1 * sn);
    }
}

// ---------------------------------------------------------------------------
// MFMA flash attention v10: 32x32x16 MFMA, 32 q-rows per wave (128 q / block).
// Halves per-q LDS traffic, barrier count, staging, and K/V refetch vs v9.
// Grid 512 all-co-resident: bh = (id&7)+8*((id>>3)&3) keeps the confirmed
// XCD cohort; t = hi5<8 ? hi5 : 23-hi5 pairs tiles t and 15-t on one CU
// (ids i, i+256) so every CU gets 68 iters total.
// Layouts: A-frag row=lane&31, k=8*(lane>>5)+j; C/D row=(reg&3)+8*(reg>>2)
// +4*(lane>>5), col=lane&31. Staging identical to v9 (Kt[32][200], Vt[128][40]).
// ---------------------------------------------------------------------------
__global__ __launch_bounds__(256) void mla_attn_mfma(
    const unsigned short* __restrict__ qbuf,
    const unsigned short* __restrict__ kvb,
    const unsigned short* __restrict__ kvbuf,
    unsigned short* __restrict__ attn_out)
{
    __shared__ unsigned short Kt[2][32 * 200];
    __shared__ unsigned short Vt[2][128 * 40];
    __shared__ unsigned short Pm[4][32 * 40];

    const int id  = blockIdx.x;
    const int bh  = (id & 7) + (((id >> 3) & 3) << 3);  // same-XCD bh cohort
    const int hi5 = id >> 5;                             // 0..15
    const int t   = (hi5 < 8) ? hi5 : 23 - hi5;          // tile 0..15; pair sums 68
    const int b = bh >> 4, h = bh & 15;
    const int tid  = threadIdx.x;
    const int lane = tid & 63;
    const int w    = tid >> 6;
    const int l31  = lane & 31;
    const int hi   = lane >> 5;
    const int rowk0 = b * SEQ;

    // ---- Kt staging geometry: 768 16B chunks, 3/thread (identical to v9) ----
    int kldso[3];
    const unsigned short* ksrc[3];
    int krst[3];
#pragma unroll
    for (int j = 0; j < 3; ++j) {
        int v = tid + j * 256;
        int row = v / 24, c = v % 24;
        kldso[j] = row * 200 + c * 8;
        if (c < 16) { ksrc[j] = kvb + (size_t)(rowk0 + row) * 4096 + h * 256 + c * 8; krst[j] = 4096; }
        else        { ksrc[j] = kvbuf + (size_t)(rowk0 + row) * 576 + 512 + (c - 16) * 8; krst[j] = 576; }
    }
    // ---- Vt staging: key-pair vp (keys 2vp,2vp+1), d-chunk vdc ----
    const int vp  = tid & 15;
    const int vdc = tid >> 4;
    const unsigned short* vsrc = kvb + (size_t)(rowk0 + 2 * vp) * 4096 + h * 256 + 128 + vdc * 8;

    auto stageK = [&](int buf, const uint4& k0, const uint4& k1, const uint4& k2) {
        *(uint4*)&Kt[buf][kldso[0]] = k0;
        *(uint4*)&Kt[buf][kldso[1]] = k1;
        *(uint4*)&Kt[buf][kldso[2]] = k2;
    };
    auto stageV = [&](int buf, const uint4& va, const uint4& vb_) {
        const unsigned* ea = (const unsigned*)&va;
        const unsigned* eb = (const unsigned*)&vb_;
        unsigned short* Vd = &Vt[buf][0];
#pragma unroll
        for (int tt = 0; tt < 4; ++tt) {
            unsigned pe = (ea[tt] & 0xffffu) | (eb[tt] << 16);
            unsigned po = (ea[tt] >> 16) | (eb[tt] & 0xffff0000u);
            *(unsigned*)&Vd[(vdc * 8 + 2 * tt) * 40 + 2 * vp]     = pe;
            *(unsigned*)&Vd[(vdc * 8 + 2 * tt + 1) * 40 + 2 * vp] = po;
        }
    };

    unsigned short* Pw = Pm[w];

    const int qbase = t * 128 + w * 32;     // wave's q rows: qbase + [0,32)
    const int qrow  = qbase + l31;          // this lane's q (cols of S^T/O^T)
    const int nkb   = 4 * t + 4;
    const int itmaxw = 4 * t + w;           // wave w active while it <= itmaxw

    // Q^T B-fragments: 12 x bf16x8 (qbuf pre-scaled by log2e/sqrt(192))
    bf16x8 qf[12];
    {
        const unsigned short* qp =
            qbuf + (size_t)(rowk0 + qrow) * 3072 + h * 192 + hi * 8;
#pragma unroll
        for (int kt = 0; kt < 12; ++kt) qf[kt] = *(const bf16x8*)(qp + kt * 16);
    }

    f32x16 O[4];   // O^T frags: dblk*32 + (reg&3)+8*(reg>>2)+4*hi, col q=l31
#pragma unroll
    for (int d = 0; d < 4; ++d)
#pragma unroll
        for (int i = 0; i < 16; ++i) O[d][i] = 0.f;
    float mi = -1e30f, li = 0.f;

    uint4 pk0, pk1, pk2, pv0, pv1;

    pk0 = *(const uint4*)(ksrc[0]);
    pk1 = *(const uint4*)(ksrc[1]);
    pk2 = *(const uint4*)(ksrc[2]);
    pv0 = *(const uint4*)(vsrc);
    pv1 = *(const uint4*)(vsrc + 4096);
    stageK(0, pk0, pk1, pk2);
    stageV(0, pv0, pv1);
    __syncthreads();

#pragma unroll 1
    for (int it = 0; it < nkb; ++it) {
        const int p = it & 1;
        const int kb = it * 32;
        const bool more = (it + 1 < nkb);

        if (more) {
            const size_t koff = (size_t)(kb + 32);
            pk0 = *(const uint4*)(ksrc[0] + koff * krst[0]);
            pk1 = *(const uint4*)(ksrc[1] + koff * krst[1]);
            pk2 = *(const uint4*)(ksrc[2] + koff * krst[2]);
            pv0 = *(const uint4*)(vsrc + koff * 4096);
            pv1 = *(const uint4*)(vsrc + koff * 4096 + 4096);
        }

        if (it <= itmaxw) {
            // ---- S^T = K * Q^T (32 keys x 32 q), 12 chained 32x32x16 ----
            f32x16 S;
#pragma unroll
            for (int i = 0; i < 16; ++i) S[i] = 0.f;
            __builtin_amdgcn_s_setprio(1);
#pragma unroll
            for (int kt = 0; kt < 12; ++kt) {
                bf16x8 kf = *(const bf16x8*)&Kt[p][l31 * 200 + kt * 16 + hi * 8];
                S = __builtin_amdgcn_mfma_f32_32x32x16_bf16(kf, qf[kt], S, 0, 0, 0);
            }
            __builtin_amdgcn_s_setprio(0);

            // ---- softmax (exp2 domain): lane holds 16 keys for q = qrow ----
            float a[16];
            float mx = -1e30f;
            if (kb + 31 > qbase) {     // wave-uniform: diagonal block
#pragma unroll
                for (int i = 0; i < 16; ++i) {
                    int key = kb + (i & 3) + 8 * (i >> 2) + 4 * hi;
                    a[i] = (key <= qrow) ? S[i] : -1e30f;
                    mx = fmaxf(mx, a[i]);
                }
            } else {
#pragma unroll
                for (int i = 0; i < 16; ++i) { a[i] = S[i]; mx = fmaxf(mx, a[i]); }
            }
            mx = fmaxf(mx, __shfl_xor(mx, 32, 64));

            // defer-max: rescale only if some q-row's max grew past THR=8
            if (!__all(mx <= mi + 8.f)) {
                float mn = fmaxf(mi, mx);
                float al = __builtin_amdgcn_exp2f(mi - mn);
#pragma unroll
                for (int d = 0; d < 4; ++d)
#pragma unroll
                    for (int i = 0; i < 16; ++i) O[d][i] *= al;
                li *= al;
                mi = mn;
            }

            float pr[16], ps = 0.f;
#pragma unroll
            for (int i = 0; i < 16; ++i) {
                pr[i] = __builtin_amdgcn_exp2f(a[i] - mi);
                ps += pr[i];
            }
            ps += __shfl_xor(ps, 32, 64);
            li += ps;

            // pack P^T -> Pm[q][key]: reg group g -> keys 8g+4hi..+3
#pragma unroll
            for (int g2 = 0; g2 < 4; ++g2) {
                bf16x4v p4;
#pragma unroll
                for (int i = 0; i < 4; ++i) p4[i] = (__bf16)pr[g2 * 4 + i];
                *(bf16x4v*)&Pw[l31 * 40 + g2 * 8 + 4 * hi] = p4;
            }

            // ---- PV: O^T += V^T * P^T (two 16-key halves x 4 d-blocks) ----
            bf16x8 pb0 = *(const bf16x8*)&Pw[l31 * 40 + hi * 8];
            bf16x8 pb1 = *(const bf16x8*)&Pw[l31 * 40 + 16 + hi * 8];
            __builtin_amdgcn_s_setprio(1);
#pragma unroll
            for (int d = 0; d < 4; ++d) {
                bf16x8 v0 = *(const bf16x8*)&Vt[p][(d * 32 + l31) * 40 + hi * 8];
                bf16x8 v1 = *(const bf16x8*)&Vt[p][(d * 32 + l31) * 40 + 16 + hi * 8];
                O[d] = __builtin_amdgcn_mfma_f32_32x32x16_bf16(v0, pb0, O[d], 0, 0, 0);
                O[d] = __builtin_amdgcn_mfma_f32_32x32x16_bf16(v1, pb1, O[d], 0, 0, 0);
            }
            __builtin_amdgcn_s_setprio(0);
        }

        if (more) {
            const int q2 = 1 - p;
            stageK(q2, pk0, pk1, pk2);
            stageV(q2, pv0, pv1);
            __syncthreads();
        }
    }

    // ---- epilogue: lane holds O^T[d][q=qrow], d = dblk*32 + i + 8g + 4hi ----
    float inv = (li > 0.f) ? (1.f / li) : 0.f;
    unsigned short* orow = attn_out + (size_t)(rowk0 + qrow) * 2048 + h * 128;
#pragma unroll
    for (int d = 0; d < 4; ++d)
#pragma unroll
        for (int g2 = 0; g2 < 4; ++g2) {
            bf16x4v o;
#pragma unroll
            for (int i = 0; i < 4; ++i) o[i] = (__bf16)(O[d][g2 * 4 + i] * inv);
            *(bf16x4v*)&orow[d * 32 + g2 * 8 + 4 * hi] = o;
        }
}

// ---------------------------------------------------------------------------
extern "C" void kernel_launch(void* const* d_in, const int* in_sizes, int n_in,
                              void* d_out, int out_size, void* d_ws, size_t ws_size,
                              hipStream_t stream)
{
    char* ws = (char*)d_ws;
    size_t off = 0;
    auto alloc = [&](size_t bytes) -> void* {
        void* p = ws + off;
        off = (off + bytes + 255) & ~(size_t)255;
        return p;
    };

    int* flag = (int*)alloc(256);

    const int nx = 4096 * 2048;
    unsigned short* xb    = (unsigned short*)alloc((size_t)nx * 2);
    unsigned short* wqa   = (unsigned short*)alloc((size_t)1536 * 2048 * 2);
    unsigned short* wqab  = (unsigned short*)alloc(1536 * 2);
    unsigned short* qnw   = (unsigned short*)alloc(1536 * 2);
    unsigned short* wqb   = (unsigned short*)alloc((size_t)3072 * 1536 * 2);
    unsigned short* wqbb  = (unsigned short*)alloc(3072 * 2);
    unsigned short* wkva  = (unsigned short*)alloc((size_t)576 * 2048 * 2);
    unsigned short* wkvab = (unsigned short*)alloc(576 * 2);
    unsigned short* kvnw  = (unsigned short*)alloc(512 * 2);
    unsigned short* wkvb  = (unsigned short*)alloc((size_t)4096 * 512 * 2);
    unsigned short* wkvbb = (unsigned short*)alloc(4096 * 2);
    unsigned short* wo    = (unsigned short*)alloc((size_t)2048 * 2048 * 2);
    unsigned short* wob   = (unsigned short*)alloc(2048 * 2);

    unsigned short* qa   = (unsigned short*)alloc((size_t)4096 * 1536 * 2);
    unsigned short* qbuf = (unsigned short*)alloc((size_t)4096 * 3072 * 2);
    unsigned short* kvbf = (unsigned short*)alloc((size_t)4096 * 576 * 2);
    unsigned short* kvb  = (unsigned short*)alloc((size_t)4096 * 4096 * 2);
    unsigned short* attn = xb;  // xb dead after kv_a gemm

    const int M = 4096;
    dim3 blk(256);

    detect_dtype<<<dim3(1), dim3(64), 0, stream>>>((const unsigned*)d_in[3], flag);

    {
        CvtArgs a;
        unsigned short* dsts[13] = {xb, wqa, wqab, qnw, wqb, wqbb, wkva, wkvab, kvnw, wkvb, wkvbb, wo, wob};
        int pb = 0;
        for (int i = 0; i < 13; ++i) {
            a.src[i] = d_in[i];
            a.dst[i] = dsts[i];
            a.n[i] = in_sizes[i];
            a.startblk[i] = pb;
            pb += (in_sizes[i] + 4095) / 4096;
        }
        a.startblk[13] = pb;
        to_bf16_all<<<dim3(pb), blk, 0, stream>>>(a, flag);
    }

    auto mkg = [](const unsigned short* A, int lda, const unsigned short* W,
                  const unsigned short* bias, unsigned short* C, float* Cf, int ldc,
                  int N, int K, const int* fl, float osc) -> GemmP {
        GemmP g;
        g.A = A; g.lda = lda; g.W = W; g.bias = bias;
        g.C = C; g.Cf = Cf; g.ldc = ldc; g.N = N; g.K = K; g.flagp = fl;
        g.nbx = (N + 127) / 128;
        g.oscale = osc;
        return g;
    };

    // q_a + kv_a fused (independent, share A-operand xb): 384 + 160 blocks
    {
        GemmP gqa  = mkg(xb, 2048, wqa,  wqab,  qa,   nullptr, 1536, 1536, 2048, nullptr, 1.f);
        GemmP gkva = mkg(xb, 2048, wkva, wkvab, kvbf, nullptr, 576,  576,  2048, nullptr, 1.f);
        int nb0 = gqa.nbx * (M / 128), nb1 = gkva.nbx * (M / 128);
        gemm_two<<<dim3(nb0 + nb1), blk, 0, stream>>>(gqa, gkva, nb0);
    }

    // both rmsnorms in one launch
    rmsnorm_ip2<<<dim3(2 * M), blk, 0, stream>>>(qa, 1536, 1536, qnw,
                                                 kvbf, 576, 512, kvnw, M);

    // q_b + kv_b fused (independent): 768 + 1024 blocks.
    // q_b output pre-scaled by log2(e)/sqrt(192): softmax runs in exp2 domain
    {
        GemmP gqb  = mkg(qa,   1536, wqb,  wqbb,  qbuf, nullptr, 3072, 3072, 1536, nullptr, 0.1041175648f);
        GemmP gkvb = mkg(kvbf, 576,  wkvb, wkvbb, kvb,  nullptr, 4096, 4096, 512,  nullptr, 1.f);
        int nb0 = gqb.nbx * (M / 128), nb1 = gkvb.nbx * (M / 128);
        gemm_two<<<dim3(nb0 + nb1), blk, 0, stream>>>(gqb, gkvb, nb0);
    }

    // rope (q + kv) in one launch
    rope_ip_all<<<dim3(M), blk, 0, stream>>>(qbuf, kvbf);

    // MFMA flash attention v10 (512 blocks, XCD cohort + CU-paired tiles)
    mla_attn_mfma<<<dim3(512), blk, 0, stream>>>(qbuf, kvb, kvbf, attn);

    // out = attn @ wo^T + wo_b
    {
        GemmP gout = mkg(attn, 2048, wo, wob, nullptr, (float*)d_out, 2048, 2048, 2048, flag, 1.f);
        gemm_one<<<dim3(gout.nbx, M / 128), blk, 0, stream>>>(gout);
    }
}

// Round 8
// 440.605 us; speedup vs baseline: 1.0307x; 1.0307x over previous
//
#include <hip/hip_runtime.h>

#define SEQ 2048
#define NHEADS 16

typedef __bf16 bf16;
typedef __bf16 bf16x8 __attribute__((ext_vector_type(8)));
typedef __bf16 bf16x4v __attribute__((ext_vector_type(4)));
typedef float f32x4 __attribute__((ext_vector_type(4)));
typedef unsigned short u16x4 __attribute__((ext_vector_type(4)));
typedef unsigned short u16x8 __attribute__((ext_vector_type(8)));

static __device__ __forceinline__ float bf2f(unsigned short u) {
    union { unsigned u32; float f; } v; v.u32 = ((unsigned)u) << 16; return v.f;
}
static __device__ __forceinline__ unsigned short f2bf(float f) {
    union { float f; unsigned u; } v; v.f = f;
    unsigned u = v.u;
    unsigned r = u + 0x7fffu + ((u >> 16) & 1u);  // RNE
    return (unsigned short)(r >> 16);
}

// CK-style direct global->LDS 16B copy. LDS dest = wave-uniform base + lane*16.
static __device__ __forceinline__ void g2l16(const unsigned short* g, unsigned short* l) {
    __builtin_amdgcn_global_load_lds(
        (const __attribute__((address_space(1))) unsigned int*)(unsigned long long)g,
        (__attribute__((address_space(3))) unsigned int*)(unsigned int)(unsigned long long)l,
        16, 0, 0);
}

// XCD-cohort remap for GEMM grids (validated mechanism, r6: FETCH 259->31MB):
// all blocks of an A-row-panel (same by) land on ONE XCD (id%8 = XCD).
// Requires nby % 8 == 0 (all our GEMMs: nby = 32). Bijective.
static __device__ __forceinline__ void cohort_map(int lid, int nbx, int* bx, int* by) {
    int rank = lid >> 3;
    int q = rank / nbx;
    *by = (lid & 7) + (q << 3);
    *bx = rank - q * nbx;
}

// ---------------------------------------------------------------------------
__global__ void detect_dtype(const unsigned* __restrict__ qnw, int* __restrict__ flag) {
    if (threadIdx.x == 0 && blockIdx.x == 0)
        *flag = (qnw[0] == 0x3F800000u) ? 1 : 0;
}

struct CvtArgs {
    const void* src[13];
    unsigned short* dst[13];
    int n[13];
    int startblk[14];
};
// all n[] are multiples of 16, so vector tails are clean
__global__ __launch_bounds__(256) void to_bf16_all(CvtArgs a, const int* __restrict__ flag) {
    int bx = blockIdx.x;
    int t = 0;
    while (bx >= a.startblk[t + 1]) ++t;
    int base = (bx - a.startblk[t]) * 4096;
    int n = a.n[t];
    int hi = base + 4096; if (hi > n) hi = n;
    int cnt = hi - base;
    if (*flag) {
        const f32x4* s = (const f32x4*)a.src[t] + (base >> 2);
        u16x4* d = (u16x4*)(a.dst[t] + base);
        int c4 = cnt >> 2;
        for (int e = threadIdx.x; e < c4; e += 256) {
            f32x4 v = s[e];
            u16x4 o;
#pragma unroll
            for (int j = 0; j < 4; ++j) o[j] = f2bf(v[j]);
            d[e] = o;
        }
    } else {
        const uint4* s = (const uint4*)a.src[t] + (base >> 3);
        uint4* d = (uint4*)(a.dst[t] + base);
        int c8 = cnt >> 3;
        for (int e = threadIdx.x; e < c8; e += 256) d[e] = s[e];
    }
}

// ---------------------------------------------------------------------------
// m97-structure GEMM body, round-2 pipeline (measured best): double-buffered
// LDS, stage(next) issued before compute(cur), ONE __syncthreads per K-step.
// ---------------------------------------------------------------------------
struct GemmP {
    const unsigned short* A; int lda;
    const unsigned short* W;
    const unsigned short* bias;
    unsigned short* C; float* Cf; int ldc;
    int N; int K; const int* flagp;
    int nbx;      // tiles along N
    float oscale; // epilogue scale: out = (acc + bias) * oscale
};

static __device__ void gemm_body(const GemmP g, int bx, int by,
                                 unsigned short* Al, unsigned short* Bl)
{
    const int lane = threadIdx.x & 63;
    const int w    = threadIdx.x >> 6;
    const int r    = lane & 15;
    const int quad = lane >> 4;
    const int m0 = by << 7;
    const int n0 = bx << 7;
    const int wr = (w >> 1) << 6;
    const int wc = (w & 1) << 6;

    const int srow = lane >> 2;
    const int scol = (lane & 3) << 3;
    const int j0 = w * 2, j1 = w * 2 + 1;

    const unsigned short* a0 = g.A + (size_t)(m0 + j0 * 16 + srow) * g.lda + scol;
    const unsigned short* a1 = g.A + (size_t)(m0 + j1 * 16 + srow) * g.lda + scol;
    int bn0 = n0 + j0 * 16 + srow; if (bn0 >= g.N) bn0 = g.N - 1;
    int bn1 = n0 + j1 * 16 + srow; if (bn1 >= g.N) bn1 = g.N - 1;
    const unsigned short* b0 = g.W + (size_t)bn0 * g.K + scol;
    const unsigned short* b1 = g.W + (size_t)bn1 * g.K + scol;

    f32x4 acc[4][4];
#pragma unroll
    for (int mt = 0; mt < 4; ++mt)
#pragma unroll
        for (int nt = 0; nt < 4; ++nt) acc[mt][nt] = (f32x4){0.f, 0.f, 0.f, 0.f};

    auto stage = [&](int buf, int kb) {
        unsigned short* Ad = Al + (buf << 12);
        unsigned short* Bd = Bl + (buf << 12);
        g2l16(a0 + kb, &Ad[j0 * 512 + lane * 8]);
        g2l16(a1 + kb, &Ad[j1 * 512 + lane * 8]);
        g2l16(b0 + kb, &Bd[j0 * 512 + lane * 8]);
        g2l16(b1 + kb, &Bd[j1 * 512 + lane * 8]);
    };

    stage(0, 0);
    __syncthreads();
    int cur = 0;
    for (int kb = 0; kb < g.K; kb += 32) {
        if (kb + 32 < g.K) stage(cur ^ 1, kb + 32);   // loads fly under compute

        const unsigned short* As = Al + (cur << 12);
        const unsigned short* Bs = Bl + (cur << 12);
        bf16x8 af[4], bfr[4];
#pragma unroll
        for (int mt = 0; mt < 4; ++mt)
            af[mt] = *(const bf16x8*)&As[(wr + mt * 16 + r) * 32 + quad * 8];
#pragma unroll
        for (int nt = 0; nt < 4; ++nt)
            bfr[nt] = *(const bf16x8*)&Bs[(wc + nt * 16 + r) * 32 + quad * 8];
#pragma unroll
        for (int mt = 0; mt < 4; ++mt)
#pragma unroll
            for (int nt = 0; nt < 4; ++nt)
                acc[mt][nt] = __builtin_amdgcn_mfma_f32_16x16x32_bf16(af[mt], bfr[nt], acc[mt][nt], 0, 0, 0);

        __syncthreads();   // drains next-tile loads + protects cur
        cur ^= 1;
    }

    int outf = (g.Cf && g.flagp) ? *g.flagp : 0;
    float bv[4];
#pragma unroll
    for (int nt = 0; nt < 4; ++nt) {
        int col = n0 + wc + nt * 16 + r;
        bv[nt] = (g.bias && col < g.N) ? bf2f(g.bias[col]) : 0.f;
    }
#pragma unroll
    for (int mt = 0; mt < 4; ++mt) {
#pragma unroll
        for (int i = 0; i < 4; ++i) {
            int row = m0 + wr + mt * 16 + quad * 4 + i;
#pragma unroll
            for (int nt = 0; nt < 4; ++nt) {
                int col = n0 + wc + nt * 16 + r;
                if (col < g.N) {
                    float v = (acc[mt][nt][i] + bv[nt]) * g.oscale;
                    size_t idx = (size_t)row * g.ldc + col;
                    if (g.Cf) {
                        if (outf) g.Cf[idx] = v;
                        else      ((unsigned short*)g.Cf)[idx] = f2bf(v);
                    } else {
                        g.C[idx] = f2bf(v);
                    }
                }
            }
        }
    }
}

__global__ __launch_bounds__(256) void gemm_one(GemmP g) {
    __shared__ unsigned short Al[2 * 4096];
    __shared__ unsigned short Bl[2 * 4096];
    int bx, by;
    cohort_map(blockIdx.x, g.nbx, &bx, &by);
    gemm_body(g, bx, by, Al, Bl);
}

__global__ __launch_bounds__(256) void gemm_two(GemmP g0, GemmP g1, int nblk0) {
    __shared__ unsigned short Al[2 * 4096];
    __shared__ unsigned short Bl[2 * 4096];
    int id = blockIdx.x;
    int bx, by;
    if (id < nblk0) {
        cohort_map(id, g0.nbx, &bx, &by);          // nblk0 % 8 == 0 everywhere
        gemm_body(g0, bx, by, Al, Bl);
    } else {
        cohort_map(id - nblk0, g1.nbx, &bx, &by);
        gemm_body(g1, bx, by, Al, Bl);
    }
}

// ---------------------------------------------------------------------------
// fused rmsnorm for both lora paths (one launch), bf16x8-vectorized (G13)
__global__ __launch_bounds__(256) void rmsnorm_ip2(
    unsigned short* __restrict__ d0, int s0w, int w0w, const unsigned short* __restrict__ w0,
    unsigned short* __restrict__ d1, int s1w, int w1w, const unsigned short* __restrict__ w1,
    int rows0)
{
    __shared__ float red[256];
    int row = blockIdx.x;
    unsigned short* p; const unsigned short* wt; int stride, width;
    if (row < rows0) { p = d0; wt = w0; stride = s0w; width = w0w; }
    else { row -= rows0; p = d1; wt = w1; stride = s1w; width = w1w; }
    p += (size_t)row * stride;

    const int nv = width >> 3;
    u16x8* pv = (u16x8*)p;
    const u16x8* wv = (const u16x8*)wt;

    float ss = 0.f;
    for (int j = threadIdx.x; j < nv; j += 256) {
        u16x8 v = pv[j];
#pragma unroll
        for (int k = 0; k < 8; ++k) { float f = bf2f(v[k]); ss += f * f; }
    }
    red[threadIdx.x] = ss;
    __syncthreads();
    for (int s = 128; s > 0; s >>= 1) {
        if ((int)threadIdx.x < s) red[threadIdx.x] += red[threadIdx.x + s];
        __syncthreads();
    }
    float rstd = rsqrtf(red[0] / (float)width + 1e-6f);
    for (int j = threadIdx.x; j < nv; j += 256) {
        u16x8 v = pv[j], g = wv[j], o;
#pragma unroll
        for (int k = 0; k < 8; ++k) o[k] = f2bf(bf2f(v[k]) * rstd * bf2f(g[k]));
        pv[j] = o;
    }
}

// fused rope: 32-entry sincos LDS table per row (1 sincos per i, not per task)
__global__ __launch_bounds__(256) void rope_ip_all(
    unsigned short* __restrict__ qbuf, unsigned short* __restrict__ kvbf)
{
    __shared__ float cst[32], snt[32];
    int row = blockIdx.x;
    int s = row & (SEQ - 1);
    if (threadIdx.x < 32) {
        int i = threadIdx.x;
        float inv = exp2f(-(float)i * (13.2877123795f / 32.0f)); // 10000^(-i/32)
        float ang = (float)s * inv;
        cst[i] = cosf(ang); snt[i] = sinf(ang);
    }
    __syncthreads();
    for (int t = threadIdx.x; t < 544; t += 256) {
        int i = t & 31;
        float c = cst[i], sn = snt[i];
        unsigned short* p;
        if (t < 512) p = qbuf + (size_t)row * 3072 + (t >> 5) * 192 + 128;
        else         p = kvbf + (size_t)row * 576 + 512;
        float x1 = bf2f(p[i]), x2 = bf2f(p[i + 32]);
        p[i]      = f2bf(x1 * c - x2 * sn);
        p[i + 32] = f2bf(x2 * c + x1 * sn);
    }
}

// ---------------------------------------------------------------------------
// MFMA flash attention v9 (measured best, round 6: 111.7us, FETCH 30.8MB):
// v5 layouts, exp2-domain softmax, prescaled Q, XCD-cohort block swizzle.
// ---------------------------------------------------------------------------
__global__ __launch_bounds__(256) void mla_attn_mfma(
    const unsigned short* __restrict__ qbuf,
    const unsigned short* __restrict__ kvb,
    const unsigned short* __restrict__ kvbuf,
    unsigned short* __restrict__ attn_out)
{
    __shared__ unsigned short Kt[2][32 * 200];
    __shared__ unsigned short Vt[2][128 * 40];
    __shared__ unsigned short Pm[4][16 * 40];

    const int id    = blockIdx.x;
    const int bh    = (id & 7) + (((id >> 3) & 3) << 3);  // same-XCD bh cohort
    const int qtblk = id >> 5;                            // 0..15
    const int b = bh >> 4, h = bh & 15;
    const int tid  = threadIdx.x;
    const int lane = tid & 63;
    const int w    = tid >> 6;
    const int r    = lane & 15;
    const int quad = lane >> 4;
    const int rowk0 = b * SEQ;

    // ---- Kt staging geometry: 768 16B chunks, 3/thread ----
    int kldso[3];
    const unsigned short* ksrc[3];
    int krst[3];
#pragma unroll
    for (int j = 0; j < 3; ++j) {
        int v = tid + j * 256;
        int row = v / 24, c = v % 24;
        kldso[j] = row * 200 + c * 8;
        if (c < 16) { ksrc[j] = kvb + (size_t)(rowk0 + row) * 4096 + h * 256 + c * 8; krst[j] = 4096; }
        else        { ksrc[j] = kvbuf + (size_t)(rowk0 + row) * 576 + 512 + (c - 16) * 8; krst[j] = 576; }
    }
    // ---- Vt staging: key-pair vp (keys 2vp,2vp+1), d-chunk vdc ----
    const int vp  = tid & 15;
    const int vdc = tid >> 4;
    const unsigned short* vsrc = kvb + (size_t)(rowk0 + 2 * vp) * 4096 + h * 256 + 128 + vdc * 8;

    auto stageK = [&](int buf, const uint4& k0, const uint4& k1, const uint4& k2) {
        *(uint4*)&Kt[buf][kldso[0]] = k0;
        *(uint4*)&Kt[buf][kldso[1]] = k1;
        *(uint4*)&Kt[buf][kldso[2]] = k2;
    };
    auto stageV = [&](int buf, const uint4& va, const uint4& vb_) {
        const unsigned* ea = (const unsigned*)&va;
        const unsigned* eb = (const unsigned*)&vb_;
        unsigned short* Vd = &Vt[buf][0];
#pragma unroll
        for (int t = 0; t < 4; ++t) {
            unsigned pe = (ea[t] & 0xffffu) | (eb[t] << 16);
            unsigned po = (ea[t] >> 16) | (eb[t] & 0xffff0000u);
            *(unsigned*)&Vd[(vdc * 8 + 2 * t) * 40 + 2 * vp]     = pe;
            *(unsigned*)&Vd[(vdc * 8 + 2 * t + 1) * 40 + 2 * vp] = po;
        }
    };

    unsigned short* Pw = Pm[w];

#pragma unroll 1
    for (int half = 0; half < 2; ++half) {
        const int qt = half ? (31 - qtblk) : qtblk;
        const int qbase = qt * 64 + w * 16;     // wave's q rows: qbase + [0,16)
        const int nkb = 2 * qt + 2;
        const int itmax = 2 * qt + (w >> 1);    // waves 0,1 skip the last iter

        // Q fragments (qbuf pre-scaled by log2e/sqrt(192) in wq_b GEMM)
        bf16x8 qf[6];
        {
            const unsigned short* qp =
                qbuf + (size_t)(rowk0 + qbase + r) * 3072 + h * 192 + quad * 8;
#pragma unroll
            for (int t = 0; t < 6; ++t) qf[t] = *(const bf16x8*)(qp + t * 32);
        }

        f32x4 O[8];   // O^T frags: d = f*16 + quad*4 + i, q = r
#pragma unroll
        for (int f = 0; f < 8; ++f) O[f] = (f32x4){0.f, 0.f, 0.f, 0.f};
        float mi = -1e30f, li = 0.f;  // per-lane (q = r); log2-domain scores

        uint4 pk0, pk1, pk2, pv0, pv1;

        __syncthreads();   // protect buffers from previous half's readers
        pk0 = *(const uint4*)(ksrc[0]);
        pk1 = *(const uint4*)(ksrc[1]);
        pk2 = *(const uint4*)(ksrc[2]);
        pv0 = *(const uint4*)(vsrc);
        pv1 = *(const uint4*)(vsrc + 4096);
        stageK(0, pk0, pk1, pk2);
        stageV(0, pv0, pv1);
        __syncthreads();

#pragma unroll 1
        for (int it = 0; it < nkb; ++it) {
            const int p = it & 1;
            const int kb = it * 32;
            const bool more = (it + 1 < nkb);

            if (more) {
                const size_t koff = (size_t)(kb + 32);
                pk0 = *(const uint4*)(ksrc[0] + koff * krst[0]);
                pk1 = *(const uint4*)(ksrc[1] + koff * krst[1]);
                pk2 = *(const uint4*)(ksrc[2] + koff * krst[2]);
                pv0 = *(const uint4*)(vsrc + koff * 4096);
                pv1 = *(const uint4*)(vsrc + koff * 4096 + 4096);
            }

            if (it <= itmax) {
                // ---- S^T = K * Q^T : rows = keys, col = q = r ----
                f32x4 s0 = {0.f, 0.f, 0.f, 0.f}, s1 = {0.f, 0.f, 0.f, 0.f};
                __builtin_amdgcn_s_setprio(1);
#pragma unroll
                for (int t = 0; t < 6; ++t) {
                    bf16x8 k0 = *(const bf16x8*)&Kt[p][r * 200 + t * 32 + quad * 8];
                    bf16x8 k1 = *(const bf16x8*)&Kt[p][(16 + r) * 200 + t * 32 + quad * 8];
                    s0 = __builtin_amdgcn_mfma_f32_16x16x32_bf16(k0, qf[t], s0, 0, 0, 0);
                    s1 = __builtin_amdgcn_mfma_f32_16x16x32_bf16(k1, qf[t], s1, 0, 0, 0);
                }
                __builtin_amdgcn_s_setprio(0);

                // ---- softmax (exp2 domain), per-lane q row = qbase + r ----
                const int qrow = qbase + r;
                float a0[4], a1[4];
                float mx = -1e30f;
                if (kb + 31 > qbase) {     // wave-uniform: diagonal block
#pragma unroll
                    for (int i = 0; i < 4; ++i) {
                        a0[i] = (kb + quad * 4 + i      <= qrow) ? s0[i] : -1e30f;
                        a1[i] = (kb + 16 + quad * 4 + i <= qrow) ? s1[i] : -1e30f;
                        mx = fmaxf(mx, fmaxf(a0[i], a1[i]));
                    }
                } else {                   // fully below diagonal: no mask
#pragma unroll
                    for (int i = 0; i < 4; ++i) {
                        a0[i] = s0[i];
                        a1[i] = s1[i];
                        mx = fmaxf(mx, fmaxf(a0[i], a1[i]));
                    }
                }
                mx = fmaxf(mx, __shfl_xor(mx, 16, 64));
                mx = fmaxf(mx, __shfl_xor(mx, 32, 64));

                // defer-max: rescale only if some q-row's max grew past THR=8
                if (!__all(mx <= mi + 8.f)) {
                    float mn = fmaxf(mi, mx);
                    float al = __builtin_amdgcn_exp2f(mi - mn);
#pragma unroll
                    for (int f = 0; f < 8; ++f) O[f] *= al;
                    li *= al;
                    mi = mn;
                }

                float p0[4], p1[4], ps = 0.f;
#pragma unroll
                for (int i = 0; i < 4; ++i) {
                    p0[i] = __builtin_amdgcn_exp2f(a0[i] - mi);
                    p1[i] = __builtin_amdgcn_exp2f(a1[i] - mi);
                    ps += p0[i] + p1[i];
                }
                ps += __shfl_xor(ps, 16, 64);
                ps += __shfl_xor(ps, 32, 64);
                li += ps;

                // pack P^T (this lane's q-row r, keys quad*4+i) -> Pm[q][k]
                bf16x4v b0v, b1v;
#pragma unroll
                for (int i = 0; i < 4; ++i) {
                    b0v[i] = (__bf16)p0[i];
                    b1v[i] = (__bf16)p1[i];
                }
                *(bf16x4v*)&Pw[r * 40 + quad * 4]      = b0v;
                *(bf16x4v*)&Pw[r * 40 + 16 + quad * 4] = b1v;

                // ---- PV: O^T = V^T * P^T  (A = Vt rows d, B = Pm rows q) ----
                bf16x8 pf = *(const bf16x8*)&Pw[r * 40 + quad * 8];
                __builtin_amdgcn_s_setprio(1);
#pragma unroll
                for (int f = 0; f < 8; ++f) {
                    bf16x8 vb = *(const bf16x8*)&Vt[p][(f * 16 + r) * 40 + quad * 8];
                    O[f] = __builtin_amdgcn_mfma_f32_16x16x32_bf16(vb, pf, O[f], 0, 0, 0);
                }
                __builtin_amdgcn_s_setprio(0);
            }

            if (more) {
                const int q2 = 1 - p;
                stageK(q2, pk0, pk1, pk2);
                stageV(q2, pv0, pv1);
                __syncthreads();
            }
        }

        // ---- epilogue: lane holds O^T[d = f*16+quad*4+i][q = r] ----
        float inv = (li > 0.f) ? (1.f / li) : 0.f;
        unsigned short* orow = attn_out + (size_t)(rowk0 + qbase + r) * 2048 + h * 128;
#pragma unroll
        for (int f = 0; f < 8; ++f) {
            bf16x4v o;
#pragma unroll
            for (int i = 0; i < 4; ++i) o[i] = (__bf16)(O[f][i] * inv);
            *(bf16x4v*)&orow[f * 16 + quad * 4] = o;
        }
    }
}

// ---------------------------------------------------------------------------
extern "C" void kernel_launch(void* const* d_in, const int* in_sizes, int n_in,
                              void* d_out, int out_size, void* d_ws, size_t ws_size,
                              hipStream_t stream)
{
    char* ws = (char*)d_ws;
    size_t off = 0;
    auto alloc = [&](size_t bytes) -> void* {
        void* p = ws + off;
        off = (off + bytes + 255) & ~(size_t)255;
        return p;
    };

    int* flag = (int*)alloc(256);

    const int nx = 4096 * 2048;
    unsigned short* xb    = (unsigned short*)alloc((size_t)nx * 2);
    unsigned short* wqa   = (unsigned short*)alloc((size_t)1536 * 2048 * 2);
    unsigned short* wqab  = (unsigned short*)alloc(1536 * 2);
    unsigned short* qnw   = (unsigned short*)alloc(1536 * 2);
    unsigned short* wqb   = (unsigned short*)alloc((size_t)3072 * 1536 * 2);
    unsigned short* wqbb  = (unsigned short*)alloc(3072 * 2);
    unsigned short* wkva  = (unsigned short*)alloc((size_t)576 * 2048 * 2);
    unsigned short* wkvab = (unsigned short*)alloc(576 * 2);
    unsigned short* kvnw  = (unsigned short*)alloc(512 * 2);
    unsigned short* wkvb  = (unsigned short*)alloc((size_t)4096 * 512 * 2);
    unsigned short* wkvbb = (unsigned short*)alloc(4096 * 2);
    unsigned short* wo    = (unsigned short*)alloc((size_t)2048 * 2048 * 2);
    unsigned short* wob   = (unsigned short*)alloc(2048 * 2);

    unsigned short* qa   = (unsigned short*)alloc((size_t)4096 * 1536 * 2);
    unsigned short* qbuf = (unsigned short*)alloc((size_t)4096 * 3072 * 2);
    unsigned short* kvbf = (unsigned short*)alloc((size_t)4096 * 576 * 2);
    unsigned short* kvb  = (unsigned short*)alloc((size_t)4096 * 4096 * 2);
    unsigned short* attn = xb;  // xb dead after kv_a gemm

    const int M = 4096;
    dim3 blk(256);

    detect_dtype<<<dim3(1), dim3(64), 0, stream>>>((const unsigned*)d_in[3], flag);

    {
        CvtArgs a;
        unsigned short* dsts[13] = {xb, wqa, wqab, qnw, wqb, wqbb, wkva, wkvab, kvnw, wkvb, wkvbb, wo, wob};
        int pb = 0;
        for (int i = 0; i < 13; ++i) {
            a.src[i] = d_in[i];
            a.dst[i] = dsts[i];
            a.n[i] = in_sizes[i];
            a.startblk[i] = pb;
            pb += (in_sizes[i] + 4095) / 4096;
        }
        a.startblk[13] = pb;
        to_bf16_all<<<dim3(pb), blk, 0, stream>>>(a, flag);
    }

    auto mkg = [](const unsigned short* A, int lda, const unsigned short* W,
                  const unsigned short* bias, unsigned short* C, float* Cf, int ldc,
                  int N, int K, const int* fl, float osc) -> GemmP {
        GemmP g;
        g.A = A; g.lda = lda; g.W = W; g.bias = bias;
        g.C = C; g.Cf = Cf; g.ldc = ldc; g.N = N; g.K = K; g.flagp = fl;
        g.nbx = (N + 127) / 128;
        g.oscale = osc;
        return g;
    };

    // q_a + kv_a fused (independent, share A-operand xb): 384 + 160 blocks
    {
        GemmP gqa  = mkg(xb, 2048, wqa,  wqab,  qa,   nullptr, 1536, 1536, 2048, nullptr, 1.f);
        GemmP gkva = mkg(xb, 2048, wkva, wkvab, kvbf, nullptr, 576,  576,  2048, nullptr, 1.f);
        int nb0 = gqa.nbx * (M / 128), nb1 = gkva.nbx * (M / 128);
        gemm_two<<<dim3(nb0 + nb1), blk, 0, stream>>>(gqa, gkva, nb0);
    }

    // both rmsnorms in one launch
    rmsnorm_ip2<<<dim3(2 * M), blk, 0, stream>>>(qa, 1536, 1536, qnw,
                                                 kvbf, 576, 512, kvnw, M);

    // q_b + kv_b fused (independent): 768 + 1024 blocks.
    // q_b output pre-scaled by log2(e)/sqrt(192): softmax runs in exp2 domain
    {
        GemmP gqb  = mkg(qa,   1536, wqb,  wqbb,  qbuf, nullptr, 3072, 3072, 1536, nullptr, 0.1041175648f);
        GemmP gkvb = mkg(kvbf, 576,  wkvb, wkvbb, kvb,  nullptr, 4096, 4096, 512,  nullptr, 1.f);
        int nb0 = gqb.nbx * (M / 128), nb1 = gkvb.nbx * (M / 128);
        gemm_two<<<dim3(nb0 + nb1), blk, 0, stream>>>(gqb, gkvb, nb0);
    }

    // rope (q + kv) in one launch
    rope_ip_all<<<dim3(M), blk, 0, stream>>>(qbuf, kvbf);

    // MFMA flash attention v9 (512 blocks, XCD-cohort swizzle)
    mla_attn_mfma<<<dim3(512), blk, 0, stream>>>(qbuf, kvb, kvbf, attn);

    // out = attn @ wo^T + wo_b
    {
        GemmP gout = mkg(attn, 2048, wo, wob, nullptr, (float*)d_out, 2048, 2048, 2048, flag, 1.f);
        gemm_one<<<dim3(gout.nbx * (M / 128)), blk, 0, stream>>>(gout);
    }
}